// Round 1
// baseline (243.668 us; speedup 1.0000x reference)
//
#include <hip/hip_runtime.h>

#define B_TOT 8192
#define FT    256
#define NREL  4
#define DEG   16
#define BM    16     // output rows per block; grid = 8192/16 = 512 -> 2 blocks/CU

typedef __attribute__((ext_vector_type(8))) short bf16x8;
typedef __attribute__((ext_vector_type(4))) float f32x4;

static __device__ __forceinline__ unsigned short f2bf(float x) {
    union { float f; unsigned int u; } c; c.f = x;
    unsigned int u = c.u;
    u += 0x7fffu + ((u >> 16) & 1u);   // round-to-nearest-even
    return (unsigned short)(u >> 16);
}
static __device__ __forceinline__ float bf2f(unsigned short h) {
    union { unsigned int u; float f; } c; c.u = ((unsigned int)h) << 16;
    return c.f;
}

// ---------- kernel A: features f32 -> bf16 table (streaming, BW-floor) ----------
__global__ __launch_bounds__(256) void cvt_feat_k(const float* __restrict__ f,
                                                  unsigned short* __restrict__ fb,
                                                  int n4) {
    int i = blockIdx.x * 256 + threadIdx.x;
    if (i < n4) {
        float4 x = ((const float4*)f)[i];
        ushort4 o;
        o.x = f2bf(x.x); o.y = f2bf(x.y); o.z = f2bf(x.z); o.w = f2bf(x.w);
        ((ushort4*)fb)[i] = o;
    }
}

// ---------- kernel 0: W [4][f][o] fp32 -> Wt [4][o][f] bf16 (LDS transpose) ----------
__global__ __launch_bounds__(256) void wtrans_k(const float* __restrict__ W,
                                                unsigned short* __restrict__ Wt) {
    __shared__ float t[64][65];   // +1 pad
    int r = blockIdx.z, ft = blockIdx.y, ot = blockIdx.x;
    int c = threadIdx.x & 63, rw = threadIdx.x >> 6;
    const float* src = W + ((size_t)r * 256 + ft * 64) * 256 + ot * 64;
#pragma unroll
    for (int i = 0; i < 16; ++i) {
        int row = i * 4 + rw;
        t[row][c] = src[(size_t)row * 256 + c];     // coalesced over c
    }
    __syncthreads();
    unsigned short* dst = Wt + ((size_t)r * 256 + ot * 64) * 256 + ft * 64;
#pragma unroll
    for (int i = 0; i < 16; ++i) {
        int row = i * 4 + rw;
        dst[(size_t)row * 256 + c] = f2bf(t[c][row]); // coalesced over c
    }
}

// ---------- fused: gather+mean -> bf16 LDS tile -> MFMA GEMM -> PReLU -> rel-mean ----------
// Block: 256 threads (4 waves), 16 output rows x 256 output cols.
// Wave w: gathers rows w*4..w*4+3 per relation; computes n-slice [w*64, w*64+64).
// B fragments come straight from L2-resident Wt (0.5 MB total) - no LDS staging for B.
// MFMA operand/C-layout convention replicated from the verified incumbent:
//   a = A[m=lane&15][k0..k0+7], b = B[n=lane&15][k0..k0+7], k0 = kk*32 + (lane>>4)*8
//   D element (lane, i) -> out[row = (lane>>4)*4 + i][col = lane&15]
template <bool BF16TAB>
__global__ __launch_bounds__(256) void fused_k(const void* __restrict__ ftab_,
                                               const int* __restrict__ nidx,
                                               const unsigned short* __restrict__ Wt,
                                               const float* __restrict__ bias,
                                               const float* __restrict__ prelu,
                                               float* __restrict__ out) {
    __shared__ int shIdx[BM * NREL * DEG];          // 4 KB
    __shared__ unsigned short As[BM][FT + 8];       // 16 x 264 bf16, +8 pad
    const int tid  = threadIdx.x;
    const int lane = tid & 63, w = tid >> 6;
    const int blk  = blockIdx.x;
    const int mrow = lane & 15, quad = lane >> 4;
    const float pa = prelu[0];

    // stage all indices for this block's 16 rows: 1024 ints, one int4 per thread
    ((int4*)shIdx)[tid] = ((const int4*)(nidx + (size_t)blk * BM * NREL * DEG))[tid];
    __syncthreads();

    const int ncol = w * 64 + mrow;        // base output col for this lane (t adds t*16)
    f32x4 accO[4] = {};

    for (int r = 0; r < NREL; ++r) {
        // ---- gather + mean: 4 rows per wave, 16 random rows each ----
#pragma unroll
        for (int j = 0; j < 4; ++j) {
            const int m = w * 4 + j;
            const int* ip = shIdx + (m * NREL + r) * DEG;
            const int4 i0 = *(const int4*)(ip);
            const int4 i1 = *(const int4*)(ip + 4);
            const int4 i2 = *(const int4*)(ip + 8);
            const int4 i3 = *(const int4*)(ip + 12);
            float s0 = 0.f, s1 = 0.f, s2 = 0.f, s3 = 0.f;
            if constexpr (BF16TAB) {
                const unsigned short* fb = (const unsigned short*)ftab_;
#define ACC(nn) { const ushort4 x = ((const ushort4*)(fb + (size_t)(nn) * FT))[lane]; \
                  s0 += bf2f(x.x); s1 += bf2f(x.y); s2 += bf2f(x.z); s3 += bf2f(x.w); }
                ACC(i0.x) ACC(i0.y) ACC(i0.z) ACC(i0.w)
                ACC(i1.x) ACC(i1.y) ACC(i1.z) ACC(i1.w)
                ACC(i2.x) ACC(i2.y) ACC(i2.z) ACC(i2.w)
                ACC(i3.x) ACC(i3.y) ACC(i3.z) ACC(i3.w)
#undef ACC
            } else {
                const float* ff = (const float*)ftab_;
#define ACC(nn) { const float4 x = ((const float4*)(ff + (size_t)(nn) * FT))[lane]; \
                  s0 += x.x; s1 += x.y; s2 += x.z; s3 += x.w; }
                ACC(i0.x) ACC(i0.y) ACC(i0.z) ACC(i0.w)
                ACC(i1.x) ACC(i1.y) ACC(i1.z) ACC(i1.w)
                ACC(i2.x) ACC(i2.y) ACC(i2.z) ACC(i2.w)
                ACC(i3.x) ACC(i3.y) ACC(i3.z) ACC(i3.w)
#undef ACC
            }
            const float inv = 1.0f / 16.0f;
            ushort4 o;
            o.x = f2bf(s0 * inv); o.y = f2bf(s1 * inv);
            o.z = f2bf(s2 * inv); o.w = f2bf(s3 * inv);
            *(ushort4*)(&As[m][lane * 4]) = o;
        }
        __syncthreads();

        // ---- 16x64 GEMM slice per wave, B fragments direct from L2 ----
        const unsigned short* bp = Wt + ((size_t)(r * 256 + ncol)) * FT;
        float bv[4];
#pragma unroll
        for (int t = 0; t < 4; ++t) bv[t] = bias[r * 256 + ncol + t * 16];

        f32x4 acc[4] = {};
#pragma unroll
        for (int kk = 0; kk < 8; ++kk) {
            const int k0 = kk * 32 + quad * 8;
            const bf16x8 a  = *(const bf16x8*)(&As[mrow][k0]);
            const bf16x8 b0 = *(const bf16x8*)(bp + k0);
            const bf16x8 b1 = *(const bf16x8*)(bp + 16 * FT + k0);
            const bf16x8 b2 = *(const bf16x8*)(bp + 32 * FT + k0);
            const bf16x8 b3 = *(const bf16x8*)(bp + 48 * FT + k0);
            acc[0] = __builtin_amdgcn_mfma_f32_16x16x32_bf16(a, b0, acc[0], 0, 0, 0);
            acc[1] = __builtin_amdgcn_mfma_f32_16x16x32_bf16(a, b1, acc[1], 0, 0, 0);
            acc[2] = __builtin_amdgcn_mfma_f32_16x16x32_bf16(a, b2, acc[2], 0, 0, 0);
            acc[3] = __builtin_amdgcn_mfma_f32_16x16x32_bf16(a, b3, acc[3], 0, 0, 0);
        }
        __syncthreads();   // As reusable for next relation

        // bias + PReLU + accumulate over relations (registers only)
#pragma unroll
        for (int t = 0; t < 4; ++t)
#pragma unroll
            for (int i = 0; i < 4; ++i) {
                float h = acc[t][i] + bv[t];
                h = (h >= 0.f) ? h : pa * h;
                accO[t][i] += h;
            }
    }

    // ---- epilogue: mean over relations, store ----
    const size_t rbase = (size_t)(blk * BM + quad * 4) * 256;
#pragma unroll
    for (int t = 0; t < 4; ++t)
#pragma unroll
        for (int i = 0; i < 4; ++i)
            out[rbase + (size_t)i * 256 + ncol + t * 16] = accO[t][i] * 0.25f;
}

extern "C" void kernel_launch(void* const* d_in, const int* in_sizes, int n_in,
                              void* d_out, int out_size, void* d_ws, size_t ws_size,
                              hipStream_t stream) {
    const float* feat  = (const float*)d_in[0];   // [100000,256] f32
    const int*   nidx  = (const int*)  d_in[1];   // [8192,4,16] i32
    const float* W     = (const float*)d_in[2];   // [4,256,256] f32
    const float* bias  = (const float*)d_in[3];   // [4,256] f32
    const float* prelu = (const float*)d_in[4];   // [1] f32
    float* out = (float*)d_out;                   // [8192,256] f32

    const size_t feat_elems = (size_t)in_sizes[0];          // 25,600,000
    const size_t fb_bytes = feat_elems * 2;                 // 51.2 MB
    const size_t wt_bytes = (size_t)NREL * 256 * FT * 2;    // 0.5 MB

    if (ws_size >= fb_bytes + wt_bytes) {
        unsigned short* fb = (unsigned short*)d_ws;
        unsigned short* Wt = fb + feat_elems;
        int n4 = (int)(feat_elems / 4);
        cvt_feat_k<<<(n4 + 255) / 256, 256, 0, stream>>>(feat, fb, n4);
        wtrans_k<<<dim3(4, 4, 4), 256, 0, stream>>>(W, Wt);
        fused_k<true><<<B_TOT / BM, 256, 0, stream>>>(fb, nidx, Wt, bias, prelu, out);
    } else {
        unsigned short* Wt = (unsigned short*)d_ws;
        wtrans_k<<<dim3(4, 4, 4), 256, 0, stream>>>(W, Wt);
        fused_k<false><<<B_TOT / BM, 256, 0, stream>>>(feat, nidx, Wt, bias, prelu, out);
    }
}

// Round 2
// 229.863 us; speedup vs baseline: 1.0601x; 1.0601x over previous
//
#include <hip/hip_runtime.h>

#define B_TOT 8192
#define FT    256
#define NREL  4
#define DEG   16
#define BM    16     // output rows per block; grid = 8192/16 = 512; 1024-thread blocks -> 2 blocks/CU, 32 waves/CU

typedef __attribute__((ext_vector_type(8))) short bf16x8;
typedef __attribute__((ext_vector_type(4))) float f32x4;

static __device__ __forceinline__ unsigned short f2bf(float x) {
    union { float f; unsigned int u; } c; c.f = x;
    unsigned int u = c.u;
    u += 0x7fffu + ((u >> 16) & 1u);   // round-to-nearest-even
    return (unsigned short)(u >> 16);
}
static __device__ __forceinline__ float bf2f(unsigned short h) {
    union { unsigned int u; float f; } c; c.u = ((unsigned int)h) << 16;
    return c.f;
}

// ---------- kernel A: features f32 -> bf16 table (streaming, BW-floor) ----------
__global__ __launch_bounds__(256) void cvt_feat_k(const float* __restrict__ f,
                                                  unsigned short* __restrict__ fb,
                                                  int n4) {
    int i = blockIdx.x * 256 + threadIdx.x;
    if (i < n4) {
        float4 x = ((const float4*)f)[i];
        ushort4 o;
        o.x = f2bf(x.x); o.y = f2bf(x.y); o.z = f2bf(x.z); o.w = f2bf(x.w);
        ((ushort4*)fb)[i] = o;
    }
}

// ---------- kernel 0: W [4][f][o] fp32 -> Wt [4][o][f] bf16 (LDS transpose) ----------
__global__ __launch_bounds__(256) void wtrans_k(const float* __restrict__ W,
                                                unsigned short* __restrict__ Wt) {
    __shared__ float t[64][65];   // +1 pad
    int r = blockIdx.z, ft = blockIdx.y, ot = blockIdx.x;
    int c = threadIdx.x & 63, rw = threadIdx.x >> 6;
    const float* src = W + ((size_t)r * 256 + ft * 64) * 256 + ot * 64;
#pragma unroll
    for (int i = 0; i < 16; ++i) {
        int row = i * 4 + rw;
        t[row][c] = src[(size_t)row * 256 + c];     // coalesced over c
    }
    __syncthreads();
    unsigned short* dst = Wt + ((size_t)r * 256 + ot * 64) * 256 + ft * 64;
#pragma unroll
    for (int i = 0; i < 16; ++i) {
        int row = i * 4 + rw;
        dst[(size_t)row * 256 + c] = f2bf(t[c][row]); // coalesced over c
    }
}

// ---------- fused: gather+mean (all rels) -> LDS -> MFMA -> PReLU -> rel-mean ----------
// 1024 threads = 16 waves. Wave w gathers row w for all 4 relations (64 independent
// row-loads, batched 16-deep for MLP), then computes the 16-col output slice
// ncol = w*16 + (lane&15). ONE barrier between gather and GEMM. B direct from L2.
// MFMA convention (verified): a = A[m=lane&15][k0..k0+7], b = B[n=lane&15][k0..k0+7],
// k0 = kk*32 + (lane>>4)*8;  D elem (lane,i) -> row (lane>>4)*4+i, col lane&15.
template <bool BF16TAB>
__global__ __launch_bounds__(1024, 8) void fused_k(const void* __restrict__ ftab_,
                                                   const int* __restrict__ nidx,
                                                   const unsigned short* __restrict__ Wt,
                                                   const float* __restrict__ bias,
                                                   const float* __restrict__ prelu,
                                                   float* __restrict__ out) {
    __shared__ int shIdx[BM * NREL * DEG];            // 1024 ints, 4 KB
    __shared__ unsigned short As[NREL][BM][FT + 8];   // 4 x 16 x 264 bf16 = 33 KB
    const int tid  = threadIdx.x;
    const int lane = tid & 63, w = tid >> 6;          // w: 0..15
    const int blk  = blockIdx.x;
    const int mrow = lane & 15, quad = lane >> 4;
    const float pa = prelu[0];

    // stage this block's 1024 indices (16 rows x 4 rel x 16 deg), coalesced
    shIdx[tid] = nidx[(size_t)blk * (BM * NREL * DEG) + tid];
    __syncthreads();

    const float inv = 1.0f / 16.0f;
    if constexpr (BF16TAB) {
        const unsigned short* fb = (const unsigned short*)ftab_;
#pragma unroll
        for (int rr = 0; rr < NREL; ++rr) {
            const int* ip = shIdx + (w * NREL + rr) * DEG;
            ushort4 x[DEG];                            // statically indexed -> registers
#pragma unroll
            for (int t = 0; t < DEG; ++t)
                x[t] = ((const ushort4*)(fb + (size_t)ip[t] * FT))[lane];
            float s0 = 0.f, s1 = 0.f, s2 = 0.f, s3 = 0.f;
#pragma unroll
            for (int t = 0; t < DEG; ++t) {
                s0 += bf2f(x[t].x); s1 += bf2f(x[t].y);
                s2 += bf2f(x[t].z); s3 += bf2f(x[t].w);
            }
            ushort4 o;
            o.x = f2bf(s0 * inv); o.y = f2bf(s1 * inv);
            o.z = f2bf(s2 * inv); o.w = f2bf(s3 * inv);
            *(ushort4*)(&As[rr][w][lane * 4]) = o;     // lane-contiguous 8B: conflict-free
        }
    } else {
        const float* ff = (const float*)ftab_;
#pragma unroll
        for (int rr = 0; rr < NREL; ++rr) {
            const int* ip = shIdx + (w * NREL + rr) * DEG;
            float s0 = 0.f, s1 = 0.f, s2 = 0.f, s3 = 0.f;
#pragma unroll
            for (int h = 0; h < 2; ++h) {              // 8-deep batches (VGPR budget)
                float4 x[8];
#pragma unroll
                for (int t = 0; t < 8; ++t)
                    x[t] = ((const float4*)(ff + (size_t)ip[h * 8 + t] * FT))[lane];
#pragma unroll
                for (int t = 0; t < 8; ++t) {
                    s0 += x[t].x; s1 += x[t].y; s2 += x[t].z; s3 += x[t].w;
                }
            }
            ushort4 o;
            o.x = f2bf(s0 * inv); o.y = f2bf(s1 * inv);
            o.z = f2bf(s2 * inv); o.w = f2bf(s3 * inv);
            *(ushort4*)(&As[rr][w][lane * 4]) = o;
        }
    }
    __syncthreads();   // the only barrier between gather and GEMM

    // ---- GEMM: wave w owns cols [w*16, w*16+16); B fragments direct from L2 ----
    const int ncol = w * 16 + mrow;
    f32x4 accO = {};
#pragma unroll
    for (int r = 0; r < NREL; ++r) {
        const unsigned short* bp = Wt + ((size_t)(r * 256 + ncol)) * FT;
        const float bv = bias[r * 256 + ncol];
        f32x4 acc = {};
#pragma unroll
        for (int kk = 0; kk < 8; ++kk) {
            const int k0 = kk * 32 + quad * 8;
            const bf16x8 a = *(const bf16x8*)(&As[r][mrow][k0]);
            const bf16x8 b = *(const bf16x8*)(bp + k0);
            acc = __builtin_amdgcn_mfma_f32_16x16x32_bf16(a, b, acc, 0, 0, 0);
        }
#pragma unroll
        for (int i = 0; i < 4; ++i) {
            float h = acc[i] + bv;
            h = (h >= 0.f) ? h : pa * h;
            accO[i] += h;
        }
    }

    // ---- epilogue: mean over relations, store ----
    const size_t rbase = (size_t)(blk * BM + quad * 4) * 256 + ncol;
#pragma unroll
    for (int i = 0; i < 4; ++i)
        out[rbase + (size_t)i * 256] = accO[i] * 0.25f;
}

extern "C" void kernel_launch(void* const* d_in, const int* in_sizes, int n_in,
                              void* d_out, int out_size, void* d_ws, size_t ws_size,
                              hipStream_t stream) {
    const float* feat  = (const float*)d_in[0];   // [100000,256] f32
    const int*   nidx  = (const int*)  d_in[1];   // [8192,4,16] i32
    const float* W     = (const float*)d_in[2];   // [4,256,256] f32
    const float* bias  = (const float*)d_in[3];   // [4,256] f32
    const float* prelu = (const float*)d_in[4];   // [1] f32
    float* out = (float*)d_out;                   // [8192,256] f32

    const size_t feat_elems = (size_t)in_sizes[0];          // 25,600,000
    const size_t fb_bytes = feat_elems * 2;                 // 51.2 MB
    const size_t wt_bytes = (size_t)NREL * 256 * FT * 2;    // 0.5 MB

    if (ws_size >= fb_bytes + wt_bytes) {
        unsigned short* fb = (unsigned short*)d_ws;
        unsigned short* Wt = fb + feat_elems;
        int n4 = (int)(feat_elems / 4);
        cvt_feat_k<<<(n4 + 255) / 256, 256, 0, stream>>>(feat, fb, n4);
        wtrans_k<<<dim3(4, 4, 4), 256, 0, stream>>>(W, Wt);
        fused_k<true><<<B_TOT / BM, 1024, 0, stream>>>(fb, nidx, Wt, bias, prelu, out);
    } else {
        unsigned short* Wt = (unsigned short*)d_ws;
        wtrans_k<<<dim3(4, 4, 4), 256, 0, stream>>>(W, Wt);
        fused_k<false><<<B_TOT / BM, 1024, 0, stream>>>(feat, nidx, Wt, bias, prelu, out);
    }
}